// Round 12
// baseline (759.286 us; speedup 1.0000x reference)
//
#include <hip/hip_runtime.h>
#include <math.h>

#define N_TOK 8192
#define C_DIM 1024
#define D_DIM 3072
#define E_NUM 8
#define SEG 128
#define MAXB 136   // sum ceil(cnt_e/128) <= 128 + 8; MAXB % 4 == 0

typedef unsigned short u16;
typedef unsigned int u32;
typedef __attribute__((ext_vector_type(8))) short bf16x8;
typedef __attribute__((ext_vector_type(4))) float f32x4;

__device__ __forceinline__ u16 f2bf(float f) {
  u32 u = __builtin_bit_cast(unsigned int, f);
  u = (u + 0x7FFFu + ((u >> 16) & 1u)) >> 16;
  return (u16)u;
}

// ---------------- init: zero output (incl aux loss) + counters ----------------
__global__ void zero_init_kernel(float* __restrict__ out, int n, int* __restrict__ cnt) {
  int i = blockIdx.x * 256 + threadIdx.x;
  if (i < n) out[i] = 0.0f;
  if (i < E_NUM) cnt[i] = 0;
}

// -------- transpose+convert: in [E][R][CC] f32 -> out [E][CC][R] bf16 --------
template<int R, int CC>
__global__ __launch_bounds__(256) void transpose_conv_kernel(
    const float* __restrict__ in, u16* __restrict__ outp) {
  __shared__ float t[64][65];
  const int e = blockIdx.z;
  const int r0 = blockIdx.y * 64;
  const int c0 = blockIdx.x * 64;
  const int tid = threadIdx.x;
  const int lr = tid >> 4;
  const int lc = (tid & 15) * 4;
#pragma unroll
  for (int i = 0; i < 4; i++) {
    float4 v = *(const float4*)(in + ((size_t)e * R + r0 + lr + i * 16) * CC + c0 + lc);
    t[lr + i * 16][lc] = v.x; t[lr + i * 16][lc + 1] = v.y;
    t[lr + i * 16][lc + 2] = v.z; t[lr + i * 16][lc + 3] = v.w;
  }
  __syncthreads();
  const int orow = tid >> 3;
  const int oc = (tid & 7) * 8;
#pragma unroll
  for (int i = 0; i < 2; i++) {
    const int d = orow + i * 32;
    union { u16 s[8]; uint4 v; } o;
#pragma unroll
    for (int j = 0; j < 8; j++) o.s[j] = f2bf(t[oc + j][d]);
    *(uint4*)(outp + ((size_t)e * CC + c0 + d) * R + r0 + oc) = o.v;
  }
}

// ---------------- router: logits (fp64), top-2, scatter ----------------
__global__ void router_kernel(const float* __restrict__ x, const float* __restrict__ rw,
                              int* __restrict__ cnt, int* __restrict__ list,
                              float* __restrict__ wl) {
  const int lane = threadIdx.x & 63;
  const int n = blockIdx.x * 4 + (threadIdx.x >> 6);
  const float* xr = x + (size_t)n * C_DIM;
  double acc[E_NUM];
#pragma unroll
  for (int e = 0; e < E_NUM; e++) acc[e] = 0.0;
  for (int c = lane; c < C_DIM; c += 64) {
    float xv = xr[c];
#pragma unroll
    for (int e = 0; e < E_NUM; e++) acc[e] += (double)xv * (double)rw[e * C_DIM + c];
  }
#pragma unroll
  for (int e = 0; e < E_NUM; e++) {
    double v = acc[e];
#pragma unroll
    for (int off = 32; off > 0; off >>= 1) v += __shfl_down(v, off, 64);
    acc[e] = v;
  }
  if (lane == 0) {
    int i0 = 0;
#pragma unroll
    for (int e = 1; e < E_NUM; e++) if (acc[e] > acc[i0]) i0 = e;
    int i1 = (i0 == 0) ? 1 : 0;
#pragma unroll
    for (int e = 0; e < E_NUM; e++) if (e != i0 && acc[e] > acc[i1]) i1 = e;
    double d = acc[i0] - acc[i1];          // >= 0
    double w0 = 1.0 / (1.0 + exp(-d));     // p0/(p0+p1)
    double w1 = 1.0 - w0;
    int p0 = atomicAdd(&cnt[i0], 1);
    list[i0 * N_TOK + p0] = n; wl[i0 * N_TOK + p0] = (float)w0;
    int p1 = atomicAdd(&cnt[i1], 1);
    list[i1 * N_TOK + p1] = n; wl[i1 * N_TOK + p1] = (float)w1;
  }
}

// ---------------- prefix sum + block table (SEG-row segments) ----------------
__global__ void prefix_kernel(const int* __restrict__ cnt, int* __restrict__ rowbase,
                              int* __restrict__ btab) {
  if (threadIdx.x == 0) {
    int s = 0, nb = 0;
    for (int e = 0; e < E_NUM; e++) {
      rowbase[e] = s;
      for (int m0 = 0; m0 < cnt[e]; m0 += SEG) { btab[2 * nb] = e; btab[2 * nb + 1] = m0; nb++; }
      s += cnt[e];
    }
    for (; nb < MAXB; nb++) { btab[2 * nb] = -1; btab[2 * nb + 1] = 0; }
  }
}

// ---------------- gather + convert: Xg[rb+p] = bf16(x[list[e][p]]) ----------------
__global__ void gather_x_kernel(const float* __restrict__ x, const int* __restrict__ cnt,
                                const int* __restrict__ rowbase, const int* __restrict__ list,
                                u16* __restrict__ Xg) {
  const int e = blockIdx.y;
  const int p = blockIdx.x * 4 + (threadIdx.x >> 6);
  if (p >= cnt[e]) return;
  const int lane = threadIdx.x & 63;
  const int tok = list[e * N_TOK + p];
  const float* src = x + (size_t)tok * C_DIM;
  u16* dst = Xg + (size_t)(rowbase[e] + p) * C_DIM;
#pragma unroll
  for (int i = 0; i < 4; i++) {
    float4 v = *(const float4*)(src + lane * 4 + i * 256);
    ushort4 o;
    o.x = f2bf(v.x); o.y = f2bf(v.y); o.z = f2bf(v.z); o.w = f2bf(v.w);
    *(ushort4*)(dst + lane * 4 + i * 256) = o;
  }
}

// ---- 128x128 tile, 256 threads, 4 blocks/CU, REG-STAGED DEPTH-2 + cohorts ----
// Two K-tiles live in registers: the vmcnt wait inside each WRITE targets loads
// issued a FULL K-step earlier (~1300cy cover) -> memory latency fully hidden,
// delivery smoothed instead of barrier-locksteped bursts.
// EPI=1: h = gelu(Xg @ W1t^T + b1)     A=Xg dense rows, Wt=[E][D][C]
// EPI=2: out += w*(h @ W2t^T + b2)     A=h dense rows,  Wt=[E][C][D]
template<int NN0, int K, int EPI>
__global__ __launch_bounds__(256, 4) void gemm_d2_kernel(
    const u16* __restrict__ A, const u16* __restrict__ Wt, const float* __restrict__ bias_,
    const int* __restrict__ btab, const int* __restrict__ cnt, const int* __restrict__ rowbase,
    const int* __restrict__ list, const float* __restrict__ wl,
    u16* __restrict__ hout, float* __restrict__ out) {
  constexpr int NTOT = NN0 * 128;
  constexpr int NT = K / 32;       // K-steps (32 or 96, even)
  constexpr int NG = NN0 / 4;      // n0 cohort groups
  constexpr int TOT = MAXB * NN0;  // grid size (TOT % 8 == 0)

  __shared__ __align__(16) u16 ldsA[2 * 128 * 32];  // 16 KB
  __shared__ __align__(16) u16 ldsB[2 * 128 * 32];  // 16 KB

  // bijective XCD chunking, then 4x4 cohort decode
  const int L = (blockIdx.x & 7) * (TOT / 8) + (blockIdx.x >> 3);
  const int coh = L >> 4, r = L & 15;
  const int bxg = coh / NG;
  const int n0g = coh % NG;
  const int bx = bxg * 4 + (r & 3);
  const int n0 = (n0g * 4 + (r >> 2)) * 128;

  const int e = btab[bx * 2];
  if (e < 0) return;
  const int m0 = btab[bx * 2 + 1];
  const int count = cnt[e];
  const int rb = rowbase[e];

  const int tid = threadIdx.x;
  const int lane = tid & 63;
  const int wid = tid >> 6;
  const int wm = (wid >> 1) * 64;
  const int wn = (wid & 1) * 64;
  const int l15 = lane & 15, l4 = lane >> 4;

  // staging addresses: row = tid>>2 (+64), 16B pos = (tid&3)*8 u16. LINEAR.
  const int arow0 = tid >> 2, pos = (tid & 3) * 8;
  const u16* aptr0 = A + (size_t)(rb + min(m0 + arow0, count - 1)) * K + pos;
  const u16* aptr1 = A + (size_t)(rb + min(m0 + arow0 + 64, count - 1)) * K + pos;
  const u16* bptr0 = Wt + ((size_t)e * NTOT + n0 + arow0) * K + pos;
  const u16* bptr1 = Wt + ((size_t)e * NTOT + n0 + arow0 + 64) * K + pos;

  const int paoff = (wm + l15) * 32 + l4 * 8;
  const int pboff = (wn + l15) * 32 + l4 * 8;

  f32x4 acc[4][4];
#pragma unroll
  for (int i = 0; i < 4; i++)
#pragma unroll
    for (int j = 0; j < 4; j++) acc[i][j] = {0.f, 0.f, 0.f, 0.f};

  // two named in-flight register sets (rule #20: no runtime-indexed sets)
  uint4 sa0_0, sa1_0, sb0_0, sb1_0;   // set 0
  uint4 sa0_1, sa1_1, sb0_1, sb1_1;   // set 1

#define LOAD0(t) { const int ko = (t) * 32; \
    sa0_0 = *(const uint4*)(aptr0 + ko); sa1_0 = *(const uint4*)(aptr1 + ko); \
    sb0_0 = *(const uint4*)(bptr0 + ko); sb1_0 = *(const uint4*)(bptr1 + ko); }
#define LOAD1(t) { const int ko = (t) * 32; \
    sa0_1 = *(const uint4*)(aptr0 + ko); sa1_1 = *(const uint4*)(aptr1 + ko); \
    sb0_1 = *(const uint4*)(bptr0 + ko); sb1_1 = *(const uint4*)(bptr1 + ko); }
#define WRITE0(b) { /* compiler inserts counted vmcnt for set-0 regs only */ \
    *(uint4*)(ldsA + (b) * 4096 + tid * 8) = sa0_0; \
    *(uint4*)(ldsA + (b) * 4096 + 2048 + tid * 8) = sa1_0; \
    *(uint4*)(ldsB + (b) * 4096 + tid * 8) = sb0_0; \
    *(uint4*)(ldsB + (b) * 4096 + 2048 + tid * 8) = sb1_0; }
#define WRITE1(b) { \
    *(uint4*)(ldsA + (b) * 4096 + tid * 8) = sa0_1; \
    *(uint4*)(ldsA + (b) * 4096 + 2048 + tid * 8) = sa1_1; \
    *(uint4*)(ldsB + (b) * 4096 + tid * 8) = sb0_1; \
    *(uint4*)(ldsB + (b) * 4096 + 2048 + tid * 8) = sb1_1; }
#define LGKM_BAR { asm volatile("s_waitcnt lgkmcnt(0)"); \
    __builtin_amdgcn_sched_barrier(0); __builtin_amdgcn_s_barrier(); \
    __builtin_amdgcn_sched_barrier(0); }
#define BAR { __builtin_amdgcn_s_barrier(); __builtin_amdgcn_sched_barrier(0); }

  auto PHASE = [&](int b) {
    const u16* pa = ldsA + b * 4096 + paoff;
    const u16* pb = ldsB + b * 4096 + pboff;
    bf16x8 av[4], bv[4];
#pragma unroll
    for (int i = 0; i < 4; i++) av[i] = *(const bf16x8*)(pa + i * 512);
#pragma unroll
    for (int j = 0; j < 4; j++) bv[j] = *(const bf16x8*)(pb + j * 512);
#pragma unroll
    for (int i = 0; i < 4; i++)
#pragma unroll
      for (int j = 0; j < 4; j++)
        acc[i][j] = __builtin_amdgcn_mfma_f32_16x16x32_bf16(av[i], bv[j], acc[i][j], 0, 0, 0);
  };

  // prologue: set0 <- tile0, set1 <- tile1; publish tile0 in buf0
  LOAD0(0);
  LOAD1(1);
  WRITE0(0);          // waits vmcnt(4): set-0 loads done, set-1 still flying
  LGKM_BAR;
  // invariant E(t): buf0 = tile t published; set1 = tile t+1 in flight; set0 free
  for (int t = 0; t < NT - 2; t += 2) {
    LOAD0(t + 2);     // issue early: hidden under PHASE(t)
    PHASE(0);         // tile t from buf0
    BAR;              // everyone done reading buf1 (phase t-1) long ago; release
    WRITE1(1);        // tile t+1 -> buf1; vmcnt(4) for set-1 (issued ~1 K-step ago)
    LGKM_BAR;         // publish buf1
    LOAD1(t + 3);
    PHASE(1);         // tile t+1 from buf1
    BAR;
    WRITE0(0);        // tile t+2 -> buf0; vmcnt(4) for set-0
    LGKM_BAR;         // publish buf0 -> E(t+2)
  }
  // tail: buf0 = tile NT-2 published, set1 = tile NT-1
  PHASE(0);
  BAR;
  WRITE1(1);
  LGKM_BAR;
  PHASE(1);

#undef LOAD0
#undef LOAD1
#undef WRITE0
#undef WRITE1
#undef LGKM_BAR
#undef BAR

  // ---------------- epilogue ----------------
  if constexpr (EPI == 1) {
#pragma unroll
    for (int i = 0; i < 4; i++) {
      const int rloc = wm + i * 16 + l4 * 4;
#pragma unroll
      for (int j = 0; j < 4; j++) {
        const int col = n0 + wn + j * 16 + l15;
        const float bias = bias_[e * NTOT + col];
#pragma unroll
        for (int rr = 0; rr < 4; rr++) {
          const int m = m0 + rloc + rr;
          if (m < count) {
            float v = acc[i][j][rr] + bias;
            float g = 0.5f * v * (1.0f + erff(v * 0.70710678118654752f));
            hout[(size_t)(rb + m) * D_DIM + col] = f2bf(g);
          }
        }
      }
    }
  } else {
    const int* lst = list + e * N_TOK;
    const float* wlst = wl + e * N_TOK;
#pragma unroll
    for (int i = 0; i < 4; i++) {
      const int rloc = wm + i * 16 + l4 * 4;
#pragma unroll
      for (int j = 0; j < 4; j++) {
        const int col = n0 + wn + j * 16 + l15;
        const float bias = bias_[e * NTOT + col];
#pragma unroll
        for (int rr = 0; rr < 4; rr++) {
          const int m = m0 + rloc + rr;
          if (m < count) {
            const int tk = lst[m];
            atomicAdd(out + (size_t)tk * C_DIM + col, wlst[m] * (acc[i][j][rr] + bias));
          }
        }
      }
    }
  }
}

extern "C" void kernel_launch(void* const* d_in, const int* in_sizes, int n_in,
                              void* d_out, int out_size, void* d_ws, size_t ws_size,
                              hipStream_t stream) {
  const float* x  = (const float*)d_in[0];
  const float* rw = (const float*)d_in[1];
  const float* W1 = (const float*)d_in[2];
  const float* b1 = (const float*)d_in[3];
  const float* W2 = (const float*)d_in[4];
  const float* b2 = (const float*)d_in[5];
  float* out = (float*)d_out;

  char* ws = (char*)d_ws;
  u16* W1t    = (u16*)(ws);                      // 50,331,648 B
  u16* Xg     = (u16*)(ws + 50331648);           // 33,554,432 B (overlaid by W2t after gemm1)
  u16* W2t    = (u16*)(ws + 50331648);           // 50,331,648 B (written AFTER gemm1)
  int* cnt    = (int*)(ws + 100663296);          // 256 B
  int* rowbase= (int*)(ws + 100663552);          // 256 B
  int* list   = (int*)(ws + 100663808);          // 262,144 B
  float* wl   = (float*)(ws + 100925952);        // 262,144 B
  int* btab   = (int*)(ws + 101188096);          // 2,048 B
  u16* h      = (u16*)(ws + 101190656);          // 100,663,296 B -> end 201,853,952

  zero_init_kernel<<<(out_size + 255) / 256, 256, 0, stream>>>(out, out_size, cnt);
  router_kernel<<<N_TOK / 4, 256, 0, stream>>>(x, rw, cnt, list, wl);
  prefix_kernel<<<1, 64, 0, stream>>>(cnt, rowbase, btab);
  gather_x_kernel<<<dim3(N_TOK / 4, E_NUM), 256, 0, stream>>>(x, cnt, rowbase, list, Xg);
  // W1 [E][C][D] f32 -> W1t [E][D][C] bf16
  transpose_conv_kernel<C_DIM, D_DIM><<<dim3(D_DIM / 64, C_DIM / 64, E_NUM), 256, 0, stream>>>(W1, W1t);
  gemm_d2_kernel<24, C_DIM, 1><<<MAXB * 24, 256, 0, stream>>>(
      Xg, W1t, b1, btab, cnt, rowbase, list, wl, h, out);
  // W2 [E][D][C] f32 -> W2t [E][C][D] bf16
  transpose_conv_kernel<D_DIM, C_DIM><<<dim3(C_DIM / 64, D_DIM / 64, E_NUM), 256, 0, stream>>>(W2, W2t);
  gemm_d2_kernel<8, D_DIM, 2><<<MAXB * 8, 256, 0, stream>>>(
      h, W2t, b2, btab, cnt, rowbase, list, wl, h, out);
}

// Round 13
// 652.084 us; speedup vs baseline: 1.1644x; 1.1644x over previous
//
#include <hip/hip_runtime.h>
#include <math.h>

#define N_TOK 8192
#define C_DIM 1024
#define D_DIM 3072
#define E_NUM 8
#define SEG 128
#define MAXB 136   // sum ceil(cnt_e/128) <= 128 + 8; MAXB % 4 == 0

typedef unsigned short u16;
typedef unsigned int u32;
typedef __attribute__((ext_vector_type(8))) short bf16x8;
typedef __attribute__((ext_vector_type(4))) float f32x4;

__device__ __forceinline__ u16 f2bf(float f) {
  u32 u = __builtin_bit_cast(unsigned int, f);
  u = (u + 0x7FFFu + ((u >> 16) & 1u)) >> 16;
  return (u16)u;
}

// ---------------- init: zero output (incl aux loss) + counters ----------------
__global__ void zero_init_kernel(float* __restrict__ out, int n, int* __restrict__ cnt) {
  const int n4 = n >> 2;
  for (int i = blockIdx.x * 256 + threadIdx.x; i < n4; i += gridDim.x * 256)
    *(float4*)(out + i * 4) = make_float4(0.f, 0.f, 0.f, 0.f);
  if (blockIdx.x == 0 && threadIdx.x == 0)
    for (int i = n4 * 4; i < n; i++) out[i] = 0.0f;   // tail (aux loss elem)
  if (blockIdx.x == 0 && threadIdx.x < E_NUM) cnt[threadIdx.x] = 0;
}

// -------- transpose+convert: in [E][R][CC] f32 -> out [E][CC][R] bf16 --------
template<int R, int CC>
__global__ __launch_bounds__(256) void transpose_conv_kernel(
    const float* __restrict__ in, u16* __restrict__ outp) {
  __shared__ float t[64][65];
  const int e = blockIdx.z;
  const int r0 = blockIdx.y * 64;
  const int c0 = blockIdx.x * 64;
  const int tid = threadIdx.x;
  const int lr = tid >> 4;
  const int lc = (tid & 15) * 4;
#pragma unroll
  for (int i = 0; i < 4; i++) {
    float4 v = *(const float4*)(in + ((size_t)e * R + r0 + lr + i * 16) * CC + c0 + lc);
    t[lr + i * 16][lc] = v.x; t[lr + i * 16][lc + 1] = v.y;
    t[lr + i * 16][lc + 2] = v.z; t[lr + i * 16][lc + 3] = v.w;
  }
  __syncthreads();
  const int orow = tid >> 3;
  const int oc = (tid & 7) * 8;
#pragma unroll
  for (int i = 0; i < 2; i++) {
    const int d = orow + i * 32;
    union { u16 s[8]; uint4 v; } o;
#pragma unroll
    for (int j = 0; j < 8; j++) o.s[j] = f2bf(t[oc + j][d]);
    *(uint4*)(outp + ((size_t)e * CC + c0 + d) * R + r0 + oc) = o.v;
  }
}

// ---------------- router: logits (fp64), top-2, scatter ----------------
__global__ void router_kernel(const float* __restrict__ x, const float* __restrict__ rw,
                              int* __restrict__ cnt, int* __restrict__ list,
                              float* __restrict__ wl) {
  const int lane = threadIdx.x & 63;
  const int n = blockIdx.x * 4 + (threadIdx.x >> 6);
  const float* xr = x + (size_t)n * C_DIM;
  double acc[E_NUM];
#pragma unroll
  for (int e = 0; e < E_NUM; e++) acc[e] = 0.0;
#pragma unroll
  for (int i = 0; i < 4; i++) {
    const int c = lane * 4 + i * 256;
    float4 xv = *(const float4*)(xr + c);
#pragma unroll
    for (int e = 0; e < E_NUM; e++) {
      const float* rwe = rw + e * C_DIM + c;
      acc[e] += (double)xv.x * (double)rwe[0] + (double)xv.y * (double)rwe[1]
              + (double)xv.z * (double)rwe[2] + (double)xv.w * (double)rwe[3];
    }
  }
#pragma unroll
  for (int e = 0; e < E_NUM; e++) {
    double v = acc[e];
#pragma unroll
    for (int off = 32; off > 0; off >>= 1) v += __shfl_down(v, off, 64);
    acc[e] = v;
  }
  if (lane == 0) {
    int i0 = 0;
#pragma unroll
    for (int e = 1; e < E_NUM; e++) if (acc[e] > acc[i0]) i0 = e;
    int i1 = (i0 == 0) ? 1 : 0;
#pragma unroll
    for (int e = 0; e < E_NUM; e++) if (e != i0 && acc[e] > acc[i1]) i1 = e;
    double d = acc[i0] - acc[i1];          // >= 0
    double w0 = 1.0 / (1.0 + exp(-d));     // p0/(p0+p1)
    double w1 = 1.0 - w0;
    int p0 = atomicAdd(&cnt[i0], 1);
    list[i0 * N_TOK + p0] = n; wl[i0 * N_TOK + p0] = (float)w0;
    int p1 = atomicAdd(&cnt[i1], 1);
    list[i1 * N_TOK + p1] = n; wl[i1 * N_TOK + p1] = (float)w1;
  }
}

// ---------------- prefix sum + block table (PARALLEL: 64 lanes) ----------------
__global__ void prefix_kernel(const int* __restrict__ cnt, int* __restrict__ rowbase,
                              int* __restrict__ btab) {
  const int lane = threadIdx.x;
  int c[E_NUM], rbse[E_NUM], nseg[E_NUM], nsb[E_NUM];
  int s = 0, t = 0;
#pragma unroll
  for (int e = 0; e < E_NUM; e++) {
    c[e] = cnt[e]; rbse[e] = s; s += c[e];
    nseg[e] = (c[e] + SEG - 1) / SEG; nsb[e] = t; t += nseg[e];
  }
  if (lane < E_NUM) rowbase[lane] = rbse[lane];
  for (int i = lane; i < MAXB; i += 64) {
    int e = -1, m0 = 0;
#pragma unroll
    for (int k = 0; k < E_NUM; k++)
      if (i >= nsb[k] && i < nsb[k] + nseg[k]) { e = k; m0 = (i - nsb[k]) * SEG; }
    btab[2 * i] = e; btab[2 * i + 1] = m0;
  }
}

// ------- gather + convert (flat-row): Xg[r] = bf16(x[list[e][r-rowbase[e]]]) -------
// total routed rows == 2*N_TOK exactly; all blocks fully active.
__global__ void gather_x_kernel(const float* __restrict__ x, const int* __restrict__ rowbase,
                                const int* __restrict__ list, u16* __restrict__ Xg) {
  const int rflat = blockIdx.x * 4 + (threadIdx.x >> 6);   // 0 .. 2*N_TOK-1
  const int lane = threadIdx.x & 63;
  int e = E_NUM - 1;
#pragma unroll
  for (int k = 1; k < E_NUM; k++) if (rflat < rowbase[k]) { e = k - 1; break; }
  const int p = rflat - rowbase[e];
  const int tok = list[e * N_TOK + p];
  const float* src = x + (size_t)tok * C_DIM;
  u16* dst = Xg + (size_t)rflat * C_DIM;
#pragma unroll
  for (int i = 0; i < 4; i++) {
    float4 v = *(const float4*)(src + lane * 4 + i * 256);
    ushort4 o;
    o.x = f2bf(v.x); o.y = f2bf(v.y); o.z = f2bf(v.z); o.w = f2bf(v.w);
    *(ushort4*)(dst + lane * 4 + i * 256) = o;
  }
}

// ---- 128x128 tile, 256 threads, 4 blocks/CU, REG-STAGED (T14) + cohorts ----
// (R11 verbatim -- best measured: 229 us/GEMM, 7.3 TB/s staged delivery)
// EPI=1: h = gelu(Xg @ W1t^T + b1)     A=Xg dense rows, Wt=[E][D][C]
// EPI=2: out += w*(h @ W2t^T + b2)     A=h dense rows,  Wt=[E][C][D]
template<int NN0, int K, int EPI>
__global__ __launch_bounds__(256, 4) void gemm_rs_kernel(
    const u16* __restrict__ A, const u16* __restrict__ Wt, const float* __restrict__ bias_,
    const int* __restrict__ btab, const int* __restrict__ cnt, const int* __restrict__ rowbase,
    const int* __restrict__ list, const float* __restrict__ wl,
    u16* __restrict__ hout, float* __restrict__ out) {
  constexpr int NTOT = NN0 * 128;
  constexpr int NT = K / 32;       // K-steps
  constexpr int NG = NN0 / 4;      // n0 cohort groups
  constexpr int TOT = MAXB * NN0;  // grid size (TOT % 8 == 0)

  __shared__ __align__(16) u16 ldsA[2 * 128 * 32];  // 16 KB
  __shared__ __align__(16) u16 ldsB[2 * 128 * 32];  // 16 KB

  const int L = (blockIdx.x & 7) * (TOT / 8) + (blockIdx.x >> 3);
  const int coh = L >> 4, r = L & 15;
  const int bxg = coh / NG;
  const int n0g = coh % NG;
  const int bx = bxg * 4 + (r & 3);
  const int n0 = (n0g * 4 + (r >> 2)) * 128;

  const int e = btab[bx * 2];
  if (e < 0) return;
  const int m0 = btab[bx * 2 + 1];
  const int count = cnt[e];
  const int rb = rowbase[e];

  const int tid = threadIdx.x;
  const int lane = tid & 63;
  const int wid = tid >> 6;
  const int wm = (wid >> 1) * 64;
  const int wn = (wid & 1) * 64;
  const int l15 = lane & 15, l4 = lane >> 4;

  const int arow0 = tid >> 2, pos = (tid & 3) * 8;
  const u16* aptr0 = A + (size_t)(rb + min(m0 + arow0, count - 1)) * K + pos;
  const u16* aptr1 = A + (size_t)(rb + min(m0 + arow0 + 64, count - 1)) * K + pos;
  const u16* bptr0 = Wt + ((size_t)e * NTOT + n0 + arow0) * K + pos;
  const u16* bptr1 = Wt + ((size_t)e * NTOT + n0 + arow0 + 64) * K + pos;

  const int paoff = (wm + l15) * 32 + l4 * 8;
  const int pboff = (wn + l15) * 32 + l4 * 8;

  f32x4 acc[4][4];
#pragma unroll
  for (int i = 0; i < 4; i++)
#pragma unroll
    for (int j = 0; j < 4; j++) acc[i][j] = {0.f, 0.f, 0.f, 0.f};

  uint4 ra0, ra1, rb0, rb1;                 // in-flight staging registers
  auto LOAD = [&](int t) {
    const int ko = t * 32;
    ra0 = *(const uint4*)(aptr0 + ko);
    ra1 = *(const uint4*)(aptr1 + ko);
    rb0 = *(const uint4*)(bptr0 + ko);
    rb1 = *(const uint4*)(bptr1 + ko);
  };
  auto WRITE = [&](int b) {                  // compiler inserts vmcnt waits
    *(uint4*)(ldsA + b * 4096 + tid * 8) = ra0;
    *(uint4*)(ldsA + b * 4096 + 2048 + tid * 8) = ra1;
    *(uint4*)(ldsB + b * 4096 + tid * 8) = rb0;
    *(uint4*)(ldsB + b * 4096 + 2048 + tid * 8) = rb1;
  };

  auto PHASE = [&](int b) {
    const u16* pa = ldsA + b * 4096 + paoff;
    const u16* pb = ldsB + b * 4096 + pboff;
    bf16x8 av[4], bv[4];
#pragma unroll
    for (int i = 0; i < 4; i++) av[i] = *(const bf16x8*)(pa + i * 512);
#pragma unroll
    for (int j = 0; j < 4; j++) bv[j] = *(const bf16x8*)(pb + j * 512);
#pragma unroll
    for (int i = 0; i < 4; i++)
#pragma unroll
      for (int j = 0; j < 4; j++)
        acc[i][j] = __builtin_amdgcn_mfma_f32_16x16x32_bf16(av[i], bv[j], acc[i][j], 0, 0, 0);
  };

  LOAD(0);
  WRITE(0);
  asm volatile("s_waitcnt lgkmcnt(0)");
  __builtin_amdgcn_sched_barrier(0);

  for (int t = 0; t < NT - 1; ++t) {
    LOAD(t + 1);                         // VMEM in flight; hidden under phase t
    __builtin_amdgcn_s_barrier();        // publish WRITE(t&1) to all waves
    __builtin_amdgcn_sched_barrier(0);
    PHASE(t & 1);
    __builtin_amdgcn_s_barrier();        // all waves done reading old buf
    WRITE((t + 1) & 1);                  // vmcnt waits auto-inserted here
    asm volatile("s_waitcnt lgkmcnt(0)");
    __builtin_amdgcn_sched_barrier(0);
  }
  __builtin_amdgcn_s_barrier();
  __builtin_amdgcn_sched_barrier(0);
  PHASE((NT - 1) & 1);

  // ---------------- epilogue ----------------
  if constexpr (EPI == 1) {
#pragma unroll
    for (int i = 0; i < 4; i++) {
      const int rloc = wm + i * 16 + l4 * 4;
#pragma unroll
      for (int j = 0; j < 4; j++) {
        const int col = n0 + wn + j * 16 + l15;
        const float bias = bias_[e * NTOT + col];
#pragma unroll
        for (int rr = 0; rr < 4; rr++) {
          const int m = m0 + rloc + rr;
          if (m < count) {
            float v = acc[i][j][rr] + bias;
            float g = 0.5f * v * (1.0f + erff(v * 0.70710678118654752f));
            hout[(size_t)(rb + m) * D_DIM + col] = f2bf(g);
          }
        }
      }
    }
  } else {
    const int* lst = list + e * N_TOK;
    const float* wlst = wl + e * N_TOK;
#pragma unroll
    for (int i = 0; i < 4; i++) {
      const int rloc = wm + i * 16 + l4 * 4;
#pragma unroll
      for (int j = 0; j < 4; j++) {
        const int col = n0 + wn + j * 16 + l15;
        const float bias = bias_[e * NTOT + col];
#pragma unroll
        for (int rr = 0; rr < 4; rr++) {
          const int m = m0 + rloc + rr;
          if (m < count) {
            const int tk = lst[m];
            atomicAdd(out + (size_t)tk * C_DIM + col, wlst[m] * (acc[i][j][rr] + bias));
          }
        }
      }
    }
  }
}

extern "C" void kernel_launch(void* const* d_in, const int* in_sizes, int n_in,
                              void* d_out, int out_size, void* d_ws, size_t ws_size,
                              hipStream_t stream) {
  const float* x  = (const float*)d_in[0];
  const float* rw = (const float*)d_in[1];
  const float* W1 = (const float*)d_in[2];
  const float* b1 = (const float*)d_in[3];
  const float* W2 = (const float*)d_in[4];
  const float* b2 = (const float*)d_in[5];
  float* out = (float*)d_out;

  char* ws = (char*)d_ws;
  u16* W1t    = (u16*)(ws);                      // 50,331,648 B
  u16* Xg     = (u16*)(ws + 50331648);           // 33,554,432 B (overlaid by W2t after gemm1)
  u16* W2t    = (u16*)(ws + 50331648);           // 50,331,648 B (written AFTER gemm1)
  int* cnt    = (int*)(ws + 100663296);          // 256 B
  int* rowbase= (int*)(ws + 100663552);          // 256 B
  int* list   = (int*)(ws + 100663808);          // 262,144 B
  float* wl   = (float*)(ws + 100925952);        // 262,144 B
  int* btab   = (int*)(ws + 101188096);          // 2,048 B
  u16* h      = (u16*)(ws + 101190656);          // 100,663,296 B -> end 201,853,952

  zero_init_kernel<<<2048, 256, 0, stream>>>(out, out_size, cnt);
  router_kernel<<<N_TOK / 4, 256, 0, stream>>>(x, rw, cnt, list, wl);
  prefix_kernel<<<1, 64, 0, stream>>>(cnt, rowbase, btab);
  gather_x_kernel<<<(2 * N_TOK) / 4, 256, 0, stream>>>(x, rowbase, list, Xg);
  // W1 [E][C][D] f32 -> W1t [E][D][C] bf16
  transpose_conv_kernel<C_DIM, D_DIM><<<dim3(D_DIM / 64, C_DIM / 64, E_NUM), 256, 0, stream>>>(W1, W1t);
  gemm_rs_kernel<24, C_DIM, 1><<<MAXB * 24, 256, 0, stream>>>(
      Xg, W1t, b1, btab, cnt, rowbase, list, wl, h, out);
  // W2 [E][D][C] f32 -> W2t [E][C][D] bf16
  transpose_conv_kernel<D_DIM, C_DIM><<<dim3(C_DIM / 64, D_DIM / 64, E_NUM), 256, 0, stream>>>(W2, W2t);
  gemm_rs_kernel<8, D_DIM, 2><<<MAXB * 8, 256, 0, stream>>>(
      h, W2t, b2, btab, cnt, rowbase, list, wl, h, out);
}